// Round 1
// baseline (1420.021 us; speedup 1.0000x reference)
//
#include <hip/hip_runtime.h>

#define NN 50000
#define EE 150000
#define HH 32
#define BN_EPS 1e-5f
#define SLOPE 0.01f

// ---------------- CSR build ----------------
__global__ __launch_bounds__(256) void k_zero(int* __restrict__ cnt, float* __restrict__ stats) {
    int i = blockIdx.x * blockDim.x + threadIdx.x;
    if (i < NN + 1) cnt[i] = 0;
    if (i < 3 * 64) stats[i] = 0.0f;
}

__global__ __launch_bounds__(256) void k_count(const int* __restrict__ ei, int* __restrict__ cnt) {
    int e = blockIdx.x * blockDim.x + threadIdx.x;
    if (e < EE) atomicAdd(&cnt[ei[EE + e]], 1);   // dst = edge_index[1][e]
}

// single block, 1024 threads: exclusive scan of cnt[0..NN] -> rowptr, cursor
__global__ __launch_bounds__(1024) void k_scan(const int* __restrict__ cnt,
                                               int* __restrict__ rowptr,
                                               int* __restrict__ cursor) {
    __shared__ int part[1024];
    const int T = 1024;
    const int CH = (NN + 1 + T - 1) / T;   // 49
    int t = threadIdx.x;
    int base = t * CH;
    int s = 0;
    for (int j = 0; j < CH; ++j) {
        int idx = base + j;
        if (idx < NN + 1) s += cnt[idx];
    }
    part[t] = s;
    __syncthreads();
    for (int off = 1; off < T; off <<= 1) {
        int val = (t >= off) ? part[t - off] : 0;
        __syncthreads();
        part[t] += val;
        __syncthreads();
    }
    int run = (t == 0) ? 0 : part[t - 1];
    for (int j = 0; j < CH; ++j) {
        int idx = base + j;
        if (idx < NN + 1) {
            int c = cnt[idx];
            rowptr[idx] = run;
            cursor[idx] = run;
            run += c;
        }
    }
}

__global__ __launch_bounds__(256) void k_fill(const int* __restrict__ ei,
                                              int* __restrict__ cursor,
                                              int* __restrict__ eids) {
    int e = blockIdx.x * blockDim.x + threadIdx.x;
    if (e < EE) {
        int pos = atomicAdd(&cursor[ei[EE + e]], 1);
        eids[pos] = e;
    }
}

// ---------------- per-layer kernels ----------------
// messages: m[e,:] = sum_i h[src,i] * ( sum_k e_k*W2[k,i,:] + b2[i,:] )
__global__ __launch_bounds__(256) void k_messages(
    const float* __restrict__ h, const int* __restrict__ ei,
    const float* __restrict__ ea, const float* __restrict__ W1,
    const float* __restrict__ b1, const float* __restrict__ W2,
    const float* __restrict__ b2, float* __restrict__ m)
{
    int e = blockIdx.x * blockDim.x + threadIdx.x;
    if (e >= EE) return;
    int s = ei[e];
    float a0 = ea[2 * e], a1 = ea[2 * e + 1];

    float hv[32];
    const float4* hp = (const float4*)(h + s * 32);
#pragma unroll
    for (int q = 0; q < 8; ++q) {
        float4 t = hp[q];
        hv[4 * q] = t.x; hv[4 * q + 1] = t.y; hv[4 * q + 2] = t.z; hv[4 * q + 3] = t.w;
    }

    float acc[32];
#pragma unroll
    for (int o = 0; o < 32; ++o) acc[o] = 0.0f;

    // bias-matrix part: acc[o] += sum_i hv[i] * b2[i*32+o]
#pragma unroll
    for (int i = 0; i < 32; ++i) {
        float z = hv[i];
#pragma unroll
        for (int o = 0; o < 32; ++o) acc[o] = fmaf(z, b2[i * 32 + o], acc[o]);
    }

    for (int k = 0; k < 10; ++k) {
        float ekk = fmaf(a0, W1[k], fmaf(a1, W1[10 + k], b1[k]));
        ekk = fmaxf(ekk, 0.0f);                       // relu on edge-MLP hidden
        const float* w2k = W2 + k * 1024;
#pragma unroll
        for (int i = 0; i < 32; ++i) {
            float z = ekk * hv[i];
#pragma unroll
            for (int o = 0; o < 32; ++o) acc[o] = fmaf(z, w2k[i * 32 + o], acc[o]);
        }
    }

    float4* mp = (float4*)(m + e * 32);
#pragma unroll
    for (int q = 0; q < 8; ++q)
        mp[q] = make_float4(acc[4 * q], acc[4 * q + 1], acc[4 * q + 2], acc[4 * q + 3]);
}

// aggregate: hpre[v] = sum_{e in CSR[v]} m[e] + h[v]@root + bias; wave-reduced BN stats
__global__ __launch_bounds__(256) void k_aggregate(
    const float* __restrict__ h, const float* __restrict__ m,
    const int* __restrict__ rowptr, const int* __restrict__ eids,
    const float* __restrict__ root, const float* __restrict__ bias,
    float* __restrict__ hpre, float* __restrict__ stats)
{
    int v = blockIdx.x * blockDim.x + threadIdx.x;
    bool act = (v < NN);
    float acc[32];
#pragma unroll
    for (int o = 0; o < 32; ++o) acc[o] = 0.0f;

    if (act) {
#pragma unroll
        for (int o = 0; o < 32; ++o) acc[o] = bias[o];
        int p0 = rowptr[v], p1 = rowptr[v + 1];
        for (int p = p0; p < p1; ++p) {
            int e = eids[p];
            const float4* mp = (const float4*)(m + e * 32);
#pragma unroll
            for (int q = 0; q < 8; ++q) {
                float4 t = mp[q];
                acc[4 * q] += t.x; acc[4 * q + 1] += t.y;
                acc[4 * q + 2] += t.z; acc[4 * q + 3] += t.w;
            }
        }
        float hv[32];
        const float4* hp = (const float4*)(h + v * 32);
#pragma unroll
        for (int q = 0; q < 8; ++q) {
            float4 t = hp[q];
            hv[4 * q] = t.x; hv[4 * q + 1] = t.y; hv[4 * q + 2] = t.z; hv[4 * q + 3] = t.w;
        }
#pragma unroll
        for (int i = 0; i < 32; ++i) {
            float z = hv[i];
#pragma unroll
            for (int o = 0; o < 32; ++o) acc[o] = fmaf(z, root[i * 32 + o], acc[o]);
        }
        float4* op = (float4*)(hpre + v * 32);
#pragma unroll
        for (int q = 0; q < 8; ++q)
            op[q] = make_float4(acc[4 * q], acc[4 * q + 1], acc[4 * q + 2], acc[4 * q + 3]);
    }

    // BN statistics: wave-level reduction per channel, then f32 atomics (64 addrs)
#pragma unroll
    for (int o = 0; o < 32; ++o) {
        float s = act ? acc[o] : 0.0f;
        float q = s * s;
#pragma unroll
        for (int d = 32; d > 0; d >>= 1) {
            s += __shfl_xor(s, d);
            q += __shfl_xor(q, d);
        }
        if ((threadIdx.x & 63) == 0) {
            atomicAdd(&stats[o], s);
            atomicAdd(&stats[32 + o], q);
        }
    }
}

__global__ void k_finalize(const float* __restrict__ stats, const float* __restrict__ gamma,
                           const float* __restrict__ beta, float* __restrict__ scsh) {
    int o = threadIdx.x;
    if (o < 32) {
        double mu = (double)stats[o] / NN;
        double var = (double)stats[32 + o] / NN - mu * mu;
        float rstd = (float)(1.0 / sqrt(var + (double)BN_EPS));
        float sc = gamma[o] * rstd;
        scsh[o] = sc;
        scsh[32 + o] = beta[o] - (float)mu * sc;
    }
}

__global__ __launch_bounds__(256) void k_norm(float* __restrict__ h, const float* __restrict__ scsh) {
    int i = blockIdx.x * blockDim.x + threadIdx.x;
    if (i < NN * 8) {
        float4 v = ((float4*)h)[i];
        int c0 = (i * 4) & 31;
        v.x = fmaf(v.x, scsh[c0 + 0], scsh[32 + c0 + 0]); v.x = v.x > 0.f ? v.x : SLOPE * v.x;
        v.y = fmaf(v.y, scsh[c0 + 1], scsh[32 + c0 + 1]); v.y = v.y > 0.f ? v.y : SLOPE * v.y;
        v.z = fmaf(v.z, scsh[c0 + 2], scsh[32 + c0 + 2]); v.z = v.z > 0.f ? v.z : SLOPE * v.z;
        v.w = fmaf(v.w, scsh[c0 + 3], scsh[32 + c0 + 3]); v.w = v.w > 0.f ? v.w : SLOPE * v.w;
        ((float4*)h)[i] = v;
    }
}

__global__ __launch_bounds__(256) void k_logits(const float* __restrict__ h,
                                                const float* __restrict__ fcW,
                                                const float* __restrict__ fcb,
                                                float* __restrict__ out) {
    int v = blockIdx.x * blockDim.x + threadIdx.x;
    if (v >= NN) return;
    float hv[32];
    const float4* hp = (const float4*)(h + v * 32);
#pragma unroll
    for (int q = 0; q < 8; ++q) {
        float4 t = hp[q];
        hv[4 * q] = t.x; hv[4 * q + 1] = t.y; hv[4 * q + 2] = t.z; hv[4 * q + 3] = t.w;
    }
    float lg[13];
#pragma unroll
    for (int c = 0; c < 13; ++c) lg[c] = fcb[c];
#pragma unroll
    for (int i = 0; i < 32; ++i) {
        float z = hv[i];
#pragma unroll
        for (int c = 0; c < 13; ++c) lg[c] = fmaf(z, fcW[i * 13 + c], lg[c]);
    }
    float mx = lg[0];
#pragma unroll
    for (int c = 1; c < 13; ++c) mx = fmaxf(mx, lg[c]);
    float sum = 0.0f;
#pragma unroll
    for (int c = 0; c < 13; ++c) sum += expf(lg[c] - mx);
    float lse = mx + logf(sum);
#pragma unroll
    for (int c = 0; c < 13; ++c) out[v * 13 + c] = lg[c] - lse;
}

// ---------------- launch ----------------
extern "C" void kernel_launch(void* const* d_in, const int* in_sizes, int n_in,
                              void* d_out, int out_size, void* d_ws, size_t ws_size,
                              hipStream_t stream) {
    const float* x     = (const float*)d_in[0];
    const int*   ei    = (const int*)  d_in[1];
    const float* ea    = (const float*)d_in[2];
    const float* netW1 = (const float*)d_in[3];
    const float* netb1 = (const float*)d_in[4];
    const float* netW2 = (const float*)d_in[5];
    const float* netb2 = (const float*)d_in[6];
    const float* root  = (const float*)d_in[7];
    const float* cbias = (const float*)d_in[8];
    const float* gamma = (const float*)d_in[9];
    const float* beta  = (const float*)d_in[10];
    const float* fcW   = (const float*)d_in[11];
    const float* fcb   = (const float*)d_in[12];
    float* out = (float*)d_out;

    char* w = (char*)d_ws;
    float* m      = (float*)(w);                 // 19,200,000 B   (also reused as int cnt during CSR build)
    float* hA     = (float*)(w + 19200000);      //  6,400,000 B
    float* hB     = (float*)(w + 25600000);      //  6,400,000 B
    int*   rowptr = (int*)  (w + 32000000);      //    200,004 B (padded)
    int*   cursor = (int*)  (w + 32200064);      //    200,004 B (padded)
    int*   eids   = (int*)  (w + 32400128);      //    600,000 B
    float* stats  = (float*)(w + 33000128);      //  3*64*4 B
    float* scsh   = (float*)(w + 33001664);      //  3*64*4 B
    int*   cnt    = (int*)w;                     // overlaps m (m written only after CSR build)

    // CSR build (once per call; reused by all 3 layers)
    k_zero <<<(NN + 256) / 256, 256, 0, stream>>>(cnt, stats);
    k_count<<<(EE + 255) / 256, 256, 0, stream>>>(ei, cnt);
    k_scan <<<1, 1024, 0, stream>>>(cnt, rowptr, cursor);
    k_fill <<<(EE + 255) / 256, 256, 0, stream>>>(ei, cursor, eids);

    const float* hcur = x;
    float* bufs[2] = { hA, hB };
    for (int i = 0; i < 3; ++i) {
        float* hnext = bufs[i & 1];
        k_messages<<<(EE + 255) / 256, 256, 0, stream>>>(
            hcur, ei, ea, netW1 + i * 20, netb1 + i * 10,
            netW2 + i * 10240, netb2 + i * 1024, m);
        k_aggregate<<<(NN + 255) / 256, 256, 0, stream>>>(
            hcur, m, rowptr, eids, root + i * 1024, cbias + i * 32,
            hnext, stats + i * 64);
        k_finalize<<<1, 64, 0, stream>>>(stats + i * 64, gamma + i * 32, beta + i * 32, scsh + i * 64);
        k_norm<<<(NN * 8 + 255) / 256, 256, 0, stream>>>(hnext, scsh + i * 64);
        hcur = hnext;
    }
    k_logits<<<(NN + 255) / 256, 256, 0, stream>>>(hcur, fcW, fcb, out);
}